// Round 9
// baseline (206.704 us; speedup 1.0000x reference)
//
#include <hip/hip_runtime.h>
#include <hip/hip_bf16.h>

#define N_NODES 100000
#define N_EDGES 1600000
#define D 128
#define NBUK 500              // buckets, 200 rows each (2 blocks/CU co-resident)
#define RPB 200               // rows per bucket
#define CCAP2 3968            // slab cap (mean 3200, sigma 56.6, +13.6s)
#define C1S 32                // cnt1 stride in ints (128B line padding)
#define NBB 391               // bucket sub-grid blocks: ceil(N_EDGES/4096)

typedef float          floatx4 __attribute__((ext_vector_type(4)));
typedef __bf16         bf16x8  __attribute__((ext_vector_type(8)));
typedef unsigned short ushort8 __attribute__((ext_vector_type(8)));

__device__ __forceinline__ unsigned rotl32(unsigned x, int d) {
    return (x << d) | (x >> (32 - d));
}

// JAX threefry2x32 with key (0, 42)
__device__ __forceinline__ void threefry_0_42(unsigned c0, unsigned c1,
                                              unsigned& o0, unsigned& o1) {
    const unsigned k0 = 0u, k1 = 42u;
    const unsigned k2 = 0x1BD11BDAu ^ k0 ^ k1;
    unsigned x0 = c0 + k0;
    unsigned x1 = c1 + k1;
#define TF_R4(r0, r1, r2, r3)                      \
    x0 += x1; x1 = rotl32(x1, r0); x1 ^= x0;       \
    x0 += x1; x1 = rotl32(x1, r1); x1 ^= x0;       \
    x0 += x1; x1 = rotl32(x1, r2); x1 ^= x0;       \
    x0 += x1; x1 = rotl32(x1, r3); x1 ^= x0;
    TF_R4(13, 15, 26, 6);  x0 += k1; x1 += k2 + 1u;
    TF_R4(17, 29, 16, 24); x0 += k2; x1 += k0 + 2u;
    TF_R4(13, 15, 26, 6);  x0 += k0; x1 += k1 + 3u;
    TF_R4(17, 29, 16, 24); x0 += k1; x1 += k2 + 4u;
    TF_R4(13, 15, 26, 6);  x0 += k2; x1 += k0 + 5u;
#undef TF_R4
    o0 = x0; o1 = x1;
}

__device__ __forceinline__ bool keep_elem(unsigned i) {
    unsigned o0, o1;
    threefry_0_42(0u, i, o0, o1);
    return (((o0 ^ o1) >> 31) == 0u);
}

__device__ __forceinline__ unsigned short f32_bf16(float f) {
    unsigned u = __float_as_uint(f);
    u += 0x7fffu + ((u >> 16) & 1u);   // RNE
    return (unsigned short)(u >> 16);
}

// row / 200 via magic multiply (exact for row < 2^30)
__device__ __forceinline__ int div200(int row) {
    return (int)(__umulhi((unsigned)row, 687194768u) >> 5);
}

// ---------------- Launch 0: W -> MFMA B-fragment layout (bf16) + zero cnt1 ----------
// Wf[((ct*4+kt)*64 + l)*8 + j] = bf16(W[(kt*32 + (l>>4)*8 + j)*128 + ct*16 + (l&15)])
__global__ __launch_bounds__(256)
void k_wprep(const float* __restrict__ W, unsigned short* __restrict__ Wf,
             int* __restrict__ cnt1) {
    int g = blockIdx.x * 256 + threadIdx.x;    // 0..2047
    for (int i = g; i < NBUK * C1S; i += 2048) cnt1[i] = 0;
    int combo = g >> 6, l = g & 63;
    int ct = combo >> 2, kt = combo & 3;
    int mm = l & 15, q = l >> 4;
    unsigned short tmp[8];
#pragma unroll
    for (int j = 0; j < 8; ++j)
        tmp[j] = f32_bf16(W[(kt * 32 + q * 8 + j) * 128 + ct * 16 + mm]);
    *(ushort8*)&Wf[g * 8] = *(ushort8*)tmp;
}

// ---------------- gemm tile body (32 rows per block, W in registers) ----------------
__device__ __forceinline__ void gemm_body(const float* __restrict__ x,
                                          const unsigned short* __restrict__ Wf,
                                          unsigned short* __restrict__ hb,
                                          unsigned short (*xs)[136],
                                          int g, int t) {
    // stage x tile with dropout -> bf16
    {
        int m  = t >> 4;
        int c0 = (t & 15) * 8;
        int r0 = g * 32 + m;
        const float* pa = x + r0 * D + c0;
        const float* pb = x + (r0 + 16) * D + c0;
        float va[8], vb[8];
        *(float4*)&va[0] = ((const float4*)pa)[0];
        *(float4*)&va[4] = ((const float4*)pa)[1];
        *(float4*)&vb[0] = ((const float4*)pb)[0];
        *(float4*)&vb[4] = ((const float4*)pb)[1];
        int ibase = r0 * D + c0;
        unsigned short ta[8], tb[8];
#pragma unroll
        for (int j = 0; j < 8; ++j) {
            float fa = keep_elem((unsigned)(ibase + j))        ? 2.0f * va[j] : 0.0f;
            float fb = keep_elem((unsigned)(ibase + 2048 + j)) ? 2.0f * vb[j] : 0.0f;
            ta[j] = f32_bf16(fa);
            tb[j] = f32_bf16(fb);
        }
        *(ushort8*)&xs[m][c0]      = *(ushort8*)ta;
        *(ushort8*)&xs[16 + m][c0] = *(ushort8*)tb;
    }
    __syncthreads();

    const int w = t >> 6, l = t & 63;
    const int rt = w >> 1, ctbase = (w & 1) * 4;
    const int mm = l & 15, q = l >> 4, koff = q * 8;
    const unsigned short* xrow = &xs[rt * 16 + mm][0];
    bf16x8 af[4];
#pragma unroll
    for (int kt = 0; kt < 4; ++kt)
        af[kt] = *(const bf16x8*)(xrow + kt * 32 + koff);

    const int growbase = g * 32 + rt * 16;
#pragma unroll
    for (int ci = 0; ci < 4; ++ci) {
        int ct = ctbase + ci;
        bf16x8 wfc[4];
#pragma unroll
        for (int kt = 0; kt < 4; ++kt)
            wfc[kt] = *(const bf16x8*)&Wf[((ct * 4 + kt) * 64 + l) * 8];
        floatx4 acc = {0.f, 0.f, 0.f, 0.f};
#pragma unroll
        for (int kt = 0; kt < 4; ++kt)
            acc = __builtin_amdgcn_mfma_f32_16x16x32_bf16(af[kt], wfc[kt], acc, 0, 0, 0);
        int col = ct * 16 + mm;
#pragma unroll
        for (int reg = 0; reg < 4; ++reg) {
            int grow = growbase + q * 4 + reg;
            hb[grow * D + col] = f32_bf16(acc[reg]);
        }
    }
}

// ---------------- Launch 1: coarse scatter (blocks 0..NBB-1) + full gemm ----------
// entry.x = col | (rowlow << 17), entry.y = float bits of val
__global__ __launch_bounds__(256)
void k_mid(const float* __restrict__ x, const unsigned short* __restrict__ Wf,
           unsigned short* __restrict__ hb,
           const int* __restrict__ row, const int* __restrict__ col,
           const float* __restrict__ val, int* __restrict__ cnt1,
           int2* __restrict__ buf) {
    __shared__ __align__(16) unsigned short xs[32][136];
    __shared__ int h[NBUK];
    __shared__ int lbase[NBUK];

    const int t = threadIdx.x;
    if (blockIdx.x >= NBB) {
        gemm_body(x, Wf, hb, xs, blockIdx.x - NBB, t);
        return;
    }

    // ---- bucket scatter (4096 edges/block, 16 in registers/thread) ----
    for (int i = t; i < NBUK; i += 256) h[i] = 0;
    __syncthreads();

    int rows[16], cols[16];
    float vals[16];
    int base = blockIdx.x * 4096;
#pragma unroll
    for (int k = 0; k < 4; ++k) {
        int e4 = base + (k * 256 + t) * 4;
        if (e4 < N_EDGES) {
            *(int4*)&rows[k * 4]   = *(const int4*)(row + e4);
            *(int4*)&cols[k * 4]   = *(const int4*)(col + e4);
            *(float4*)&vals[k * 4] = *(const float4*)(val + e4);
        } else {
            rows[k * 4] = rows[k * 4 + 1] = rows[k * 4 + 2] = rows[k * 4 + 3] = -1;
        }
    }
#pragma unroll
    for (int j = 0; j < 16; ++j)
        if (rows[j] >= 0) atomicAdd(&h[div200(rows[j])], 1);
    __syncthreads();

    // reserve ranges: one padded global counter per bucket (own 128B line)
    for (int i = t; i < NBUK; i += 256) {
        int c = h[i];
        lbase[i] = c ? atomicAdd(&cnt1[i * C1S], c) : 0;
    }
    __syncthreads();
    for (int i = t; i < NBUK; i += 256) h[i] = 0;
    __syncthreads();

#pragma unroll
    for (int j = 0; j < 16; ++j) {
        if (rows[j] >= 0) {
            int bb  = div200(rows[j]);
            int pos = lbase[bb] + atomicAdd(&h[bb], 1);
            if (pos < CCAP2) {
                int2 ent;
                ent.x = cols[j] | ((rows[j] - bb * RPB) << 17);
                ent.y = __float_as_int(vals[j]);
                buf[bb * CCAP2 + pos] = ent;
            }
        }
    }
}

// ---------------- Launch 2: per-bucket sort + gather + ReLU (2 blocks/CU) ----------
// 1024 threads. Stage slab->regs, 16-wave 200-bin hist, scan, scatter sorted to LDS,
// then wave w gathers rows {w, w+16, w+32, ...}.
__global__ __launch_bounds__(1024, 8)
void k_megagather(const int* __restrict__ cnt1, const int2* __restrict__ buf,
                  const unsigned short* __restrict__ hb, float* __restrict__ out) {
    __shared__ int h[16][201];
    __shared__ int rs_[201];
    __shared__ int wsum[4];
    __shared__ __align__(16) int2 eL[CCAP2];

    const int c = blockIdx.x, t = threadIdx.x, w = t >> 6;
    int n = cnt1[c * C1S];
    if (n > CCAP2) n = CCAP2;
    const int2* slab = buf + (size_t)c * CCAP2;

    for (int i = t; i < 16 * 201; i += 1024) ((int*)h)[i] = 0;
    __syncthreads();

    // stage entries to registers + per-wave histogram (<=4 per thread)
    int2 er[4];
#pragma unroll
    for (int k = 0; k < 4; ++k) {
        int i = k * 1024 + t;
        if (i < n) {
            er[k] = slab[i];
            atomicAdd(&h[w][((unsigned)er[k].x) >> 17], 1);
        }
    }
    __syncthreads();

    // 201-bin exclusive scan (threads 0..255; bin 200 sums to n)
    int v = 0;
    if (t < 201) {
        for (int wv = 0; wv < 16; ++wv) v += h[wv][t];
    }
    int xsc = v;
    if (t < 256) {
#pragma unroll
        for (int off = 1; off < 64; off <<= 1) {
            int u = __shfl_up(xsc, off);
            if ((t & 63) >= off) xsc += u;
        }
        if ((t & 63) == 63) wsum[w] = xsc;
    }
    __syncthreads();
    if (t < 201) {
        int wo = 0;
        for (int k = 0; k < w; ++k) wo += wsum[k];
        int basex = xsc - v + wo;          // exclusive prefix = row start
        rs_[t] = basex;                    // rs_[200] = n
        int s = basex;                     // per-wave scatter cursors
        for (int wv = 0; wv < 16; ++wv) {
            int tmp = h[wv][t];
            h[wv][t] = s;
            s += tmp;
        }
    }
    __syncthreads();

    // counting-sort scatter (regs -> LDS, sorted by rowlow)
#pragma unroll
    for (int k = 0; k < 4; ++k) {
        int i = k * 1024 + t;
        if (i < n) {
            int pos = atomicAdd(&h[w][((unsigned)er[k].x) >> 17], 1);
            eL[pos] = er[k];
        }
    }
    __syncthreads();

    // gather: wave w -> rows {w, w+16, ...}; lane -> cols l2, l2+1
    const int l2 = (t & 63) * 2;
    const unsigned short* hbl = hb + l2;
    for (int rl = w; rl < RPB; rl += 16) {
        int s0 = rs_[rl];
        int cc = rs_[rl + 1] - s0;
        float a0 = 0.f, a1 = 0.f;
        int i = 0;
        for (; i + 16 <= cc; i += 16) {
            unsigned ex[16];
            float    vv[16];
#pragma unroll
            for (int j = 0; j < 16; ++j) {
                int2 e = eL[s0 + i + j];
                ex[j] = ((unsigned)e.x & 0x1FFFFu) << 7;   // col*128 halfword offset
                vv[j] = __int_as_float(e.y);
            }
            unsigned hv[16];
#pragma unroll
            for (int j = 0; j < 16; ++j)
                hv[j] = *(const unsigned*)(hbl + ex[j]);
#pragma unroll
            for (int j = 0; j < 16; ++j) {
                a0 = fmaf(vv[j], __uint_as_float(hv[j] << 16), a0);
                a1 = fmaf(vv[j], __uint_as_float(hv[j] & 0xffff0000u), a1);
            }
        }
        for (; i + 4 <= cc; i += 4) {
            unsigned ex[4];
            float    vv[4];
#pragma unroll
            for (int j = 0; j < 4; ++j) {
                int2 e = eL[s0 + i + j];
                ex[j] = ((unsigned)e.x & 0x1FFFFu) << 7;
                vv[j] = __int_as_float(e.y);
            }
            unsigned hv[4];
#pragma unroll
            for (int j = 0; j < 4; ++j)
                hv[j] = *(const unsigned*)(hbl + ex[j]);
#pragma unroll
            for (int j = 0; j < 4; ++j) {
                a0 = fmaf(vv[j], __uint_as_float(hv[j] << 16), a0);
                a1 = fmaf(vv[j], __uint_as_float(hv[j] & 0xffff0000u), a1);
            }
        }
        for (; i < cc; ++i) {
            int2 e = eL[s0 + i];
            float v2 = __int_as_float(e.y);
            unsigned hv = *(const unsigned*)(hbl + (((unsigned)e.x & 0x1FFFFu) << 7));
            a0 = fmaf(v2, __uint_as_float(hv << 16), a0);
            a1 = fmaf(v2, __uint_as_float(hv & 0xffff0000u), a1);
        }
        int grow = c * RPB + rl;           // always < N_NODES (500*200 = 100000)
        float2 rr;
        rr.x = a0 > 0.f ? a0 : 0.f;
        rr.y = a1 > 0.f ? a1 : 0.f;
        *(float2*)(out + grow * D + l2) = rr;
    }
}

extern "C" void kernel_launch(void* const* d_in, const int* in_sizes, int n_in,
                              void* d_out, int out_size, void* d_ws, size_t ws_size,
                              hipStream_t stream) {
    const float* x    = (const float*)d_in[0];
    const float* W    = (const float*)d_in[1];
    const int*   arow = (const int*)d_in[2];
    const int*   acol = (const int*)d_in[3];
    const float* aval = (const float*)d_in[4];
    float* out = (float*)d_out;

    char* ws = (char*)d_ws;
    unsigned short* hb = (unsigned short*)ws;            // 25,600,000 B
    size_t off = 25600000;
    int* cnt1 = (int*)(ws + off); off += NBUK * C1S * 4; // 64,000 B (padded counters)
    off = (off + 127) & ~(size_t)127;
    unsigned short* Wf = (unsigned short*)(ws + off); off += 32768;  // W frag layout
    off = (off + 127) & ~(size_t)127;
    int2* buf = (int2*)(ws + off); off += (size_t)NBUK * CCAP2 * 8;  // 15.87 MB
    // total ~41.6 MB

    k_wprep      <<<8, 256, 0, stream>>>(W, Wf, cnt1);
    k_mid        <<<NBB + 3125, 256, 0, stream>>>(x, Wf, hb, arow, acol, aval, cnt1, buf);
    k_megagather <<<NBUK, 1024, 0, stream>>>(cnt1, buf, hb, out);
}

// Round 11
// 204.188 us; speedup vs baseline: 1.0123x; 1.0123x over previous
//
#include <hip/hip_runtime.h>
#include <hip/hip_bf16.h>

#define N_NODES 100000
#define N_EDGES 1600000
#define D 128
#define NBUK 250              // coarse buckets, 400 rows each (one per CU)
#define RPB 400               // rows per bucket
#define CCAP2 7360            // slab cap (mean 6400, sigma 80, +12s)
#define C1S 32                // cnt1 stride in ints (128B line padding)
#define NBB 391               // bucket sub-grid blocks: ceil(N_EDGES/4096)

typedef float          floatx4 __attribute__((ext_vector_type(4)));
typedef __bf16         bf16x8  __attribute__((ext_vector_type(8)));
typedef unsigned short ushort8 __attribute__((ext_vector_type(8)));

__device__ __forceinline__ unsigned rotl32(unsigned x, int d) {
    return (x << d) | (x >> (32 - d));
}

// JAX threefry2x32 with key (0, 42)
__device__ __forceinline__ void threefry_0_42(unsigned c0, unsigned c1,
                                              unsigned& o0, unsigned& o1) {
    const unsigned k0 = 0u, k1 = 42u;
    const unsigned k2 = 0x1BD11BDAu ^ k0 ^ k1;
    unsigned x0 = c0 + k0;
    unsigned x1 = c1 + k1;
#define TF_R4(r0, r1, r2, r3)                      \
    x0 += x1; x1 = rotl32(x1, r0); x1 ^= x0;       \
    x0 += x1; x1 = rotl32(x1, r1); x1 ^= x0;       \
    x0 += x1; x1 = rotl32(x1, r2); x1 ^= x0;       \
    x0 += x1; x1 = rotl32(x1, r3); x1 ^= x0;
    TF_R4(13, 15, 26, 6);  x0 += k1; x1 += k2 + 1u;
    TF_R4(17, 29, 16, 24); x0 += k2; x1 += k0 + 2u;
    TF_R4(13, 15, 26, 6);  x0 += k0; x1 += k1 + 3u;
    TF_R4(17, 29, 16, 24); x0 += k1; x1 += k2 + 4u;
    TF_R4(13, 15, 26, 6);  x0 += k2; x1 += k0 + 5u;
#undef TF_R4
    o0 = x0; o1 = x1;
}

__device__ __forceinline__ bool keep_elem(unsigned i) {
    unsigned o0, o1;
    threefry_0_42(0u, i, o0, o1);
    return (((o0 ^ o1) >> 31) == 0u);
}

__device__ __forceinline__ unsigned short f32_bf16(float f) {
    unsigned u = __float_as_uint(f);
    u += 0x7fffu + ((u >> 16) & 1u);   // RNE
    return (unsigned short)(u >> 16);
}

// row / 400 via magic multiply (exact for row < 2^17)
__device__ __forceinline__ int div400(int row) {
    return (int)(__umulhi((unsigned)row, 687194768u) >> 6);
}

// ---------------- Launch 0: W -> MFMA B-fragment layout (bf16) + zero cnt1 ----------
// Wf[((ct*4+kt)*64 + l)*8 + j] = bf16(W[(kt*32 + (l>>4)*8 + j)*128 + ct*16 + (l&15)])
__global__ __launch_bounds__(256)
void k_wprep(const float* __restrict__ W, unsigned short* __restrict__ Wf,
             int* __restrict__ cnt1) {
    int g = blockIdx.x * 256 + threadIdx.x;    // 0..2047
    for (int i = g; i < NBUK * C1S; i += 2048) cnt1[i] = 0;
    int combo = g >> 6, l = g & 63;
    int ct = combo >> 2, kt = combo & 3;
    int mm = l & 15, q = l >> 4;
    unsigned short tmp[8];
#pragma unroll
    for (int j = 0; j < 8; ++j)
        tmp[j] = f32_bf16(W[(kt * 32 + q * 8 + j) * 128 + ct * 16 + mm]);
    *(ushort8*)&Wf[g * 8] = *(ushort8*)tmp;
}

// ---------------- gemm tile body (32 rows per block, W in registers) ----------------
__device__ __forceinline__ void gemm_body(const float* __restrict__ x,
                                          const unsigned short* __restrict__ Wf,
                                          unsigned short* __restrict__ hb,
                                          unsigned short (*xs)[136],
                                          int g, int t) {
    // stage x tile with dropout -> bf16
    {
        int m  = t >> 4;
        int c0 = (t & 15) * 8;
        int r0 = g * 32 + m;
        const float* pa = x + r0 * D + c0;
        const float* pb = x + (r0 + 16) * D + c0;
        float va[8], vb[8];
        *(float4*)&va[0] = ((const float4*)pa)[0];
        *(float4*)&va[4] = ((const float4*)pa)[1];
        *(float4*)&vb[0] = ((const float4*)pb)[0];
        *(float4*)&vb[4] = ((const float4*)pb)[1];
        int ibase = r0 * D + c0;
        unsigned short ta[8], tb[8];
#pragma unroll
        for (int j = 0; j < 8; ++j) {
            float fa = keep_elem((unsigned)(ibase + j))        ? 2.0f * va[j] : 0.0f;
            float fb = keep_elem((unsigned)(ibase + 2048 + j)) ? 2.0f * vb[j] : 0.0f;
            ta[j] = f32_bf16(fa);
            tb[j] = f32_bf16(fb);
        }
        *(ushort8*)&xs[m][c0]      = *(ushort8*)ta;
        *(ushort8*)&xs[16 + m][c0] = *(ushort8*)tb;
    }
    __syncthreads();

    const int w = t >> 6, l = t & 63;
    const int rt = w >> 1, ctbase = (w & 1) * 4;
    const int mm = l & 15, q = l >> 4, koff = q * 8;
    const unsigned short* xrow = &xs[rt * 16 + mm][0];
    bf16x8 af[4];
#pragma unroll
    for (int kt = 0; kt < 4; ++kt)
        af[kt] = *(const bf16x8*)(xrow + kt * 32 + koff);

    const int growbase = g * 32 + rt * 16;
#pragma unroll
    for (int ci = 0; ci < 4; ++ci) {
        int ct = ctbase + ci;
        bf16x8 wfc[4];
#pragma unroll
        for (int kt = 0; kt < 4; ++kt)
            wfc[kt] = *(const bf16x8*)&Wf[((ct * 4 + kt) * 64 + l) * 8];
        floatx4 acc = {0.f, 0.f, 0.f, 0.f};
#pragma unroll
        for (int kt = 0; kt < 4; ++kt)
            acc = __builtin_amdgcn_mfma_f32_16x16x32_bf16(af[kt], wfc[kt], acc, 0, 0, 0);
        int col = ct * 16 + mm;
#pragma unroll
        for (int reg = 0; reg < 4; ++reg) {
            int grow = growbase + q * 4 + reg;
            hb[grow * D + col] = f32_bf16(acc[reg]);
        }
    }
}

// ---------------- Launch 1: coarse scatter (blocks 0..NBB-1) + full gemm ----------
// entry.x = col | (rowlow9 << 17), entry.y = float bits of val
__global__ __launch_bounds__(256)
void k_mid(const float* __restrict__ x, const unsigned short* __restrict__ Wf,
           unsigned short* __restrict__ hb,
           const int* __restrict__ row, const int* __restrict__ col,
           const float* __restrict__ val, int* __restrict__ cnt1,
           int2* __restrict__ buf) {
    __shared__ __align__(16) unsigned short xs[32][136];
    __shared__ int h[NBUK];
    __shared__ int lbase[NBUK];

    const int t = threadIdx.x;
    if (blockIdx.x >= NBB) {
        gemm_body(x, Wf, hb, xs, blockIdx.x - NBB, t);
        return;
    }

    // ---- bucket scatter (4096 edges/block, 16 in registers/thread) ----
    if (t < NBUK) h[t] = 0;
    __syncthreads();

    int rows[16], cols[16];
    float vals[16];
    int base = blockIdx.x * 4096;
#pragma unroll
    for (int k = 0; k < 4; ++k) {
        int e4 = base + (k * 256 + t) * 4;
        if (e4 < N_EDGES) {
            *(int4*)&rows[k * 4]   = *(const int4*)(row + e4);
            *(int4*)&cols[k * 4]   = *(const int4*)(col + e4);
            *(float4*)&vals[k * 4] = *(const float4*)(val + e4);
        } else {
            rows[k * 4] = rows[k * 4 + 1] = rows[k * 4 + 2] = rows[k * 4 + 3] = -1;
        }
    }
#pragma unroll
    for (int j = 0; j < 16; ++j)
        if (rows[j] >= 0) atomicAdd(&h[div400(rows[j])], 1);
    __syncthreads();

    // reserve ranges: one padded global counter per bucket (own 128B line)
    if (t < NBUK) {
        int c = h[t];
        lbase[t] = c ? atomicAdd(&cnt1[t * C1S], c) : 0;
        h[t] = 0;
    }
    __syncthreads();

#pragma unroll
    for (int j = 0; j < 16; ++j) {
        if (rows[j] >= 0) {
            int bb  = div400(rows[j]);
            int pos = lbase[bb] + atomicAdd(&h[bb], 1);
            if (pos < CCAP2) {
                int2 ent;
                ent.x = cols[j] | ((rows[j] - bb * RPB) << 17);
                ent.y = __float_as_int(vals[j]);
                buf[bb * CCAP2 + pos] = ent;
            }
        }
    }
}

// ---------------- Launch 2: per-bucket sort + gather + ReLU (one block per CU) -------
// 1024 threads. Stage slab->regs, 16-wave 400-bin hist, scan, scatter sorted to LDS,
// then wave w gathers rows [25w, 25w+25).
__global__ __launch_bounds__(1024, 4)
void k_megagather(const int* __restrict__ cnt1, const int2* __restrict__ buf,
                  const unsigned short* __restrict__ hb, float* __restrict__ out) {
    __shared__ int h[16][401];
    __shared__ int rs_[401];
    __shared__ int wsum[8];
    __shared__ __align__(16) int2 eL[CCAP2];

    const int c = blockIdx.x, t = threadIdx.x, w = t >> 6;
    int n = cnt1[c * C1S];
    if (n > CCAP2) n = CCAP2;
    const int2* slab = buf + (size_t)c * CCAP2;

    for (int i = t; i < 16 * 401; i += 1024) ((int*)h)[i] = 0;
    __syncthreads();

    // stage entries to registers + per-wave histogram (<=8 per thread)
    int2 er[8];
#pragma unroll
    for (int k = 0; k < 8; ++k) {
        int i = k * 1024 + t;
        if (i < n) {
            er[k] = slab[i];
            atomicAdd(&h[w][((unsigned)er[k].x) >> 17], 1);
        }
    }
    __syncthreads();

    // 400-bin exclusive scan (waves 0..6; bins 400..447 are zero pads)
    int v = 0;
    if (t < 401) {
        for (int wv = 0; wv < 16; ++wv) v += h[wv][t];
    }
    int xsc = v;
    if (t < 448) {
#pragma unroll
        for (int off = 1; off < 64; off <<= 1) {
            int u = __shfl_up(xsc, off);
            if ((t & 63) >= off) xsc += u;
        }
        if ((t & 63) == 63) wsum[w] = xsc;
    }
    __syncthreads();
    if (t < 401) {
        int wo = 0;
        for (int k = 0; k < w; ++k) wo += wsum[k];
        int basex = xsc - v + wo;          // exclusive prefix = row start
        rs_[t] = basex;
        int s = basex;                     // per-wave scatter cursors
        for (int wv = 0; wv < 16; ++wv) {
            int tmp = h[wv][t];
            h[wv][t] = s;
            s += tmp;
        }
    }
    __syncthreads();

    // counting-sort scatter (regs -> LDS, sorted by rowlow)
#pragma unroll
    for (int k = 0; k < 8; ++k) {
        int i = k * 1024 + t;
        if (i < n) {
            int pos = atomicAdd(&h[w][((unsigned)er[k].x) >> 17], 1);
            eL[pos] = er[k];
        }
    }
    __syncthreads();

    // gather: wave w -> rows [25w, 25w+25); lane -> cols l2, l2+1
    const int l2 = (t & 63) * 2;
    const unsigned short* hbl = hb + l2;
    for (int r = 0; r < 25; ++r) {
        int rl = w * 25 + r;
        int s0 = rs_[rl];
        int cc = rs_[rl + 1] - s0;
        float a0 = 0.f, a1 = 0.f;
        int i = 0;
        for (; i + 16 <= cc; i += 16) {
            unsigned ex[16];
            float    vv[16];
#pragma unroll
            for (int j = 0; j < 16; ++j) {
                int2 e = eL[s0 + i + j];
                ex[j] = ((unsigned)e.x & 0x1FFFFu) << 7;   // col*128 halfword offset
                vv[j] = __int_as_float(e.y);
            }
            unsigned hv[16];
#pragma unroll
            for (int j = 0; j < 16; ++j)
                hv[j] = *(const unsigned*)(hbl + ex[j]);
#pragma unroll
            for (int j = 0; j < 16; ++j) {
                a0 = fmaf(vv[j], __uint_as_float(hv[j] << 16), a0);
                a1 = fmaf(vv[j], __uint_as_float(hv[j] & 0xffff0000u), a1);
            }
        }
        for (; i + 4 <= cc; i += 4) {
            unsigned ex[4];
            float    vv[4];
#pragma unroll
            for (int j = 0; j < 4; ++j) {
                int2 e = eL[s0 + i + j];
                ex[j] = ((unsigned)e.x & 0x1FFFFu) << 7;
                vv[j] = __int_as_float(e.y);
            }
            unsigned hv[4];
#pragma unroll
            for (int j = 0; j < 4; ++j)
                hv[j] = *(const unsigned*)(hbl + ex[j]);
#pragma unroll
            for (int j = 0; j < 4; ++j) {
                a0 = fmaf(vv[j], __uint_as_float(hv[j] << 16), a0);
                a1 = fmaf(vv[j], __uint_as_float(hv[j] & 0xffff0000u), a1);
            }
        }
        for (; i < cc; ++i) {
            int2 e = eL[s0 + i];
            float v2 = __int_as_float(e.y);
            unsigned hv = *(const unsigned*)(hbl + (((unsigned)e.x & 0x1FFFFu) << 7));
            a0 = fmaf(v2, __uint_as_float(hv << 16), a0);
            a1 = fmaf(v2, __uint_as_float(hv & 0xffff0000u), a1);
        }
        int grow = c * RPB + rl;           // always < N_NODES (250*400 = 100000)
        float2 rr;
        rr.x = a0 > 0.f ? a0 : 0.f;
        rr.y = a1 > 0.f ? a1 : 0.f;
        *(float2*)(out + grow * D + l2) = rr;
    }
}

extern "C" void kernel_launch(void* const* d_in, const int* in_sizes, int n_in,
                              void* d_out, int out_size, void* d_ws, size_t ws_size,
                              hipStream_t stream) {
    const float* x    = (const float*)d_in[0];
    const float* W    = (const float*)d_in[1];
    const int*   arow = (const int*)d_in[2];
    const int*   acol = (const int*)d_in[3];
    const float* aval = (const float*)d_in[4];
    float* out = (float*)d_out;

    char* ws = (char*)d_ws;
    unsigned short* hb = (unsigned short*)ws;            // 25,600,000 B
    size_t off = 25600000;
    int* cnt1 = (int*)(ws + off); off += NBUK * C1S * 4; // 32,000 B (padded counters)
    off = (off + 127) & ~(size_t)127;
    unsigned short* Wf = (unsigned short*)(ws + off); off += 32768;  // W frag layout
    off = (off + 127) & ~(size_t)127;
    int2* buf = (int2*)(ws + off); off += (size_t)NBUK * CCAP2 * 8;  // 14.72 MB
    // total ~40.4 MB

    k_wprep      <<<8, 256, 0, stream>>>(W, Wf, cnt1);
    k_mid        <<<NBB + 3125, 256, 0, stream>>>(x, Wf, hb, arow, acol, aval, cnt1, buf);
    k_megagather <<<NBUK, 1024, 0, stream>>>(cnt1, buf, hb, out);
}